// Round 8
// baseline (1593.506 us; speedup 1.0000x reference)
//
#include <hip/hip_runtime.h>
#include <hip/hip_fp16.h>

#define NB   256
#define NS   1024
#define NI   64
#define NH   128
#define NCLS 10

typedef _Float16 h1;
typedef h1 h2 __attribute__((ext_vector_type(2)));
struct alignas(16) H8 { h2 v[4]; };

// Operand vector = 256 f16 [x_h(64) | m(64) | h(128)], split into 4 chunks of
// 64 f16; chunk stride padded to 144 B (72 h1) so the 4 chunks' ds_read_b128
// hit disjoint bank groups ({0-3},{4-7},{8-11},{12-15}): conflict-free.
#define CH_H1  72
#define BUF_H1 (4 * CH_H1)

__device__ __forceinline__ h2 pk(float a, float b) {
  return __builtin_bit_cast(h2, __builtin_amdgcn_cvt_pkrtz(a, b));
}

__device__ __forceinline__ float fdot2(h2 a, h2 b, float c) {
#if __has_builtin(__builtin_amdgcn_fdot2)
  return __builtin_amdgcn_fdot2(a, b, c, false);
#else
  return c + (float)a[0] * (float)b[0] + (float)a[1] * (float)b[1];
#endif
}

__device__ __forceinline__ float fast_rcp(float x) {
#if __has_builtin(__builtin_amdgcn_rcpf)
  return __builtin_amdgcn_rcpf(x);
#else
  return 1.0f / x;
#endif
}

__device__ __forceinline__ float tanh_f(float x) {
  return 2.f * fast_rcp(1.f + __expf(-2.f * x)) - 1.f;
}
__device__ __forceinline__ float sigm(float x) {
  return fast_rcp(1.f + __expf(-x));
}

// VALU-pipe cross-lane add via DPP.
template<int CTRL>
__device__ __forceinline__ float dpp_add(float x) {
  int y = __builtin_amdgcn_update_dpp(0, __float_as_int(x), CTRL, 0xF, 0xF, true);
  return x + __int_as_float(y);
}
// all-reduce sum over each aligned 4-lane quad; bit-identical on all 4 lanes.
__device__ __forceinline__ float red4(float x) {
  x = dpp_add<0xB1>(x);   // quad_perm {1,0,3,2}
  x = dpp_add<0x4E>(x);   // quad_perm {2,3,0,1}
  return x;
}

__global__ __launch_bounds__(512, 2) void grud_fused(
    const float* __restrict__ values,
    const int*   __restrict__ masks,
    const float* __restrict__ deltas,
    const float* __restrict__ W_dh, const float* __restrict__ b_dh,
    const float* __restrict__ W_dx, const float* __restrict__ b_dx,
    const float* __restrict__ W_ih, const float* __restrict__ W_hh,
    const float* __restrict__ b_ih, const float* __restrict__ b_hh,
    const float* __restrict__ W_out, const float* __restrict__ b_out,
    float* __restrict__ out)
{
  const int b   = blockIdx.x;          // batch row
  const int tid = threadIdx.x;         // 0..511
  const int l   = tid & 63;
  const int w   = tid >> 6;            // wave 0..7
  const int q   = l & 3;               // K-chunk 0..3 (64 elems each)
  const int u   = (w << 4) | (l >> 2); // hidden unit 0..127

  __shared__ alignas(16) h1 opA[BUF_H1];
  __shared__ alignas(16) h1 opB[BUF_H1];
  __shared__ float hfin[NH];

  // ---- per-thread weights: 4 gates x 64 f16 (chunk q of [x_h|m|h]) ----
  h2 wt[4][32];
#pragma unroll
  for (int g = 0; g < 4; ++g) {
    const int row = g * NH + u;
    const float* src = (q < 2) ? (W_ih + (size_t)row * 128 + 64 * q)
                               : (W_hh + (size_t)row * 128 + 64 * (q - 2));
    const float4* s4 = reinterpret_cast<const float4*>(src);
#pragma unroll
    for (int k = 0; k < 16; ++k) {
      float4 f = s4[k];
      wt[g][2 * k]     = pk(f.x, f.y);
      wt[g][2 * k + 1] = pk(f.z, f.w);
    }
  }
  // biases pre-scaled by 0.25: acc init on all 4 quad lanes sums to bias.
  const float bs0 = 0.25f * (b_ih[u]          + b_hh[u]);
  const float bs1 = 0.25f * (b_ih[NH + u]     + b_hh[NH + u]);
  const float bs2 = 0.25f * (b_ih[2 * NH + u] + b_hh[2 * NH + u]);
  const float bs3 = 0.25f * (b_ih[3 * NH + u] + b_hh[3 * NH + u]);
  // gamma_h weights: unit u, elems [16q, 16q+16)
  h2 wdh[8];
  {
    const float4* a4 = reinterpret_cast<const float4*>(W_dh + u * 64 + 16 * q);
#pragma unroll
    for (int k = 0; k < 4; ++k) {
      float4 f = a4[k];
      wdh[2 * k]     = pk(f.x, f.y);
      wdh[2 * k + 1] = pk(f.z, f.w);
    }
  }
  const float bdh4 = 0.25f * b_dh[u];
  float wdx_i = 0.f, bdx_i = 0.f;
  if (tid < NI) { wdx_i = W_dx[tid * 64 + tid]; bdx_i = b_dx[tid]; }

  const size_t base_b = (size_t)b * NS * NI;
  float* out_y   = out;
  float* out_imp = out + NB * NCLS;

  // ---- prologue: zero h region, build inp[0], impute[0] ----
  if (tid < NH) {
    int e = 128 + tid;
    opA[CH_H1 * (e >> 6) + (e & 63)] = (h1)0.f;
  }
  if (tid < NI) {
    float x0 = values[base_b + tid];
    float m0 = (float)masks[base_b + tid];
    float d0 = deltas[base_b + tid];
    float gx = __expf(-fmaxf(d0 * wdx_i + bdx_i, 0.f));
    float xh = m0 * x0 + (1.f - m0) * (1.f - gx);
    out_imp[base_b + tid] = xh;
    opA[tid]         = (h1)xh;   // elem tid     -> chunk 0
    opA[CH_H1 + tid] = (h1)m0;   // elem 64+tid  -> chunk 1
  }

  h1* cur = opA;
  h1* nxt = opB;
  float c_st = 0.f, h_st = 0.f;

  for (int t = 0; t < NS; ++t) {
    __syncthreads();
    const int    tn = (t + 1 < NS) ? (t + 1) : (NS - 1);
    const size_t nb = base_b + (size_t)tn * NI;

    // prefetch next-step gamma_h chunk (16 floats) + impute inputs (wave 0)
    const float4* dn4 = reinterpret_cast<const float4*>(deltas + nb + 16 * q);
    float4 pd0 = dn4[0], pd1 = dn4[1], pd2 = dn4[2], pd3 = dn4[3];
    float px = 0.f, pm = 0.f, pdv = 0.f;
    if (tid < NI) {
      px  = values[nb + tid];
      pm  = (float)masks[nb + tid];
      pdv = deltas[nb + tid];
    }

    // operand chunk q: 64 f16 = 8 x b128 (conflict-free, 16-lane broadcast)
    const H8* s8 = reinterpret_cast<const H8*>(cur + CH_H1 * q);
    H8 o[8];
#pragma unroll
    for (int p = 0; p < 8; ++p) o[p] = s8[p];

    // 4 gates x 32 dot2 (independent chains), bias folded into init
    float a0 = bs0, a1 = bs1, a2 = bs2, a3 = bs3;
#pragma unroll
    for (int p = 0; p < 8; ++p) {
#pragma unroll
      for (int v = 0; v < 4; ++v) {
        a0 = fdot2(o[p].v[v], wt[0][4 * p + v], a0);
        a1 = fdot2(o[p].v[v], wt[1][4 * p + v], a1);
        a2 = fdot2(o[p].v[v], wt[2][4 * p + v], a2);
        a3 = fdot2(o[p].v[v], wt[3][4 * p + v], a3);
      }
    }

    // 4-lane reduce on the VALU pipe; all quad lanes get all 4 gates
    float gi = red4(a0);
    float gf = red4(a1);
    float gg = red4(a2);
    float go = red4(a3);

    float ia = sigm(gi);
    float fa = sigm(gf);
    float ga = tanh_f(gg);
    float oa = sigm(go);

    c_st = fa * c_st + ia * ga;
    h_st = oa * tanh_f(c_st);

    // gamma_h(t+1): 16 elems/lane + red4
    h2 p0 = pk(pd0.x, pd0.y), p1 = pk(pd0.z, pd0.w);
    h2 p2 = pk(pd1.x, pd1.y), p3 = pk(pd1.z, pd1.w);
    h2 p4 = pk(pd2.x, pd2.y), p5 = pk(pd2.z, pd2.w);
    h2 p6 = pk(pd3.x, pd3.y), p7 = pk(pd3.z, pd3.w);
    float part = bdh4;
    part = fdot2(p0, wdh[0], part);
    part = fdot2(p1, wdh[1], part);
    part = fdot2(p2, wdh[2], part);
    part = fdot2(p3, wdh[3], part);
    part = fdot2(p4, wdh[4], part);
    part = fdot2(p5, wdh[5], part);
    part = fdot2(p6, wdh[6], part);
    part = fdot2(p7, wdh[7], part);
    part = red4(part);
    float gh = __expf(-fmaxf(part, 0.f));

    // build next operand buffer
    if (tid < NI) {
      float gx = __expf(-fmaxf(pdv * wdx_i + bdx_i, 0.f));
      float xh = pm * px + (1.f - pm) * (1.f - gx);
      if (t + 1 < NS) out_imp[nb + tid] = xh;
      nxt[tid]         = (h1)xh;
      nxt[CH_H1 + tid] = (h1)pm;
    }
    if (q == 0) {
      int e = 128 + u;
      nxt[CH_H1 * (e >> 6) + (e & 63)] = (h1)(h_st * gh);
    }

    h1* tmp = cur; cur = nxt; nxt = tmp;
  }

  // ---- epilogue: y_h = h_final @ W_out^T + b_out ----
  if (q == 0) hfin[u] = h_st;
  __syncthreads();
  if (tid < NCLS) {
    float acc = b_out[tid];
    const float4* wo4 = reinterpret_cast<const float4*>(W_out + tid * NH);
#pragma unroll
    for (int k = 0; k < 32; ++k) {
      float4 a = wo4[k];
      acc += a.x * hfin[4 * k] + a.y * hfin[4 * k + 1] +
             a.z * hfin[4 * k + 2] + a.w * hfin[4 * k + 3];
    }
    out_y[b * NCLS + tid] = acc;
  }
}

extern "C" void kernel_launch(void* const* d_in, const int* in_sizes, int n_in,
                              void* d_out, int out_size, void* d_ws, size_t ws_size,
                              hipStream_t stream) {
  (void)in_sizes; (void)n_in; (void)d_ws; (void)ws_size; (void)out_size;
  grud_fused<<<dim3(NB), dim3(512), 0, stream>>>(
      (const float*)d_in[0],  (const int*)d_in[1],   (const float*)d_in[2],
      (const float*)d_in[3],  (const float*)d_in[4], (const float*)d_in[5],
      (const float*)d_in[6],  (const float*)d_in[7], (const float*)d_in[8],
      (const float*)d_in[9],  (const float*)d_in[10],(const float*)d_in[11],
      (const float*)d_in[12], (float*)d_out);
}